// Round 1
// baseline (18103.502 us; speedup 1.0000x reference)
//
#include <hip/hip_runtime.h>

typedef __attribute__((ext_vector_type(8))) short short8;
typedef __attribute__((ext_vector_type(4))) float f32x4;

// Problem constants
#define S_ 512
#define B_ 64
#define E_ 256
#define H_ 256
#define NSTEP 1023  // 2*S - 1 sequential cell steps per chain

// ---------- helpers ----------
__device__ __forceinline__ short f2bf(float f) {
  unsigned u = __builtin_bit_cast(unsigned, f);
  unsigned r = (u + 0x7fffu + ((u >> 16) & 1u)) >> 16;  // RNE
  return (short)r;
}
__device__ __forceinline__ float sigm(float x) { return 1.f / (1.f + __expf(-x)); }
__device__ __forceinline__ float tanh_(float x) {
  x = fminf(fmaxf(x, -15.f), 15.f);
  float e = __expf(-2.f * x);
  return (1.f - e) / (1.f + e);
}

// ---------- prep: cast x to bf16; pack [Wih|Whh] rows in (jc*4+gate) order; combine biases ----------
__global__ __launch_bounds__(256) void prep_kernel(
    const float* __restrict__ x,
    const float* __restrict__ wih_f, const float* __restrict__ whh_f,
    const float* __restrict__ bih_f, const float* __restrict__ bhh_f,
    const float* __restrict__ wih_b, const float* __restrict__ whh_b,
    const float* __restrict__ bih_b, const float* __restrict__ bhh_b,
    short* __restrict__ x_bf, short* __restrict__ w_pack, float* __restrict__ bias_p)
{
  long i0 = (long)blockIdx.x * blockDim.x + threadIdx.x;
  long stride = (long)gridDim.x * blockDim.x;
  const long NX = (long)S_ * B_ * E_;      // 8,388,608
  const long NW = 2L * 1024 * 512;         // 1,048,576
  const long NB = 2L * 1024;

  for (long i = i0; i < NX; i += stride) x_bf[i] = f2bf(x[i]);

  for (long i = i0; i < NW; i += stride) {
    int ch  = (int)(i >> 19);        // 1024*512 = 2^19
    int rem = (int)(i & 524287);
    int p   = rem >> 9;              // packed row 0..1023
    int k   = rem & 511;             // 0..511
    int jc  = p >> 2, g = p & 3;
    int j   = g * 256 + jc;          // original gate row (i,f,g,o blocks of 256)
    const float* wih = ch ? wih_b : wih_f;
    const float* whh = ch ? whh_b : whh_f;
    float v = (k < 256) ? wih[(long)j * 256 + k] : whh[(long)j * 256 + (k - 256)];
    w_pack[i] = f2bf(v);
  }

  for (long i = i0; i < NB; i += stride) {
    int ch = (int)(i >> 10);
    int p  = (int)(i & 1023);
    int jc = p >> 2, g = p & 3;
    int j  = g * 256 + jc;
    bias_p[i] = ch ? (bih_b[j] + bhh_b[j]) : (bih_f[j] + bhh_f[j]);
  }
}

// ---------- sequential bi-chain LSTM ----------
// grid = 8 blocks: block = (chain ch = bid>>2) x (group g = bid&3), 512 threads (8 waves).
// Wave owns 8 h-cols = 2 MFMA M-tiles of packed rows; weights live in VGPRs for all 1023 steps.
__global__ __launch_bounds__(512) void lstm_seq(
    const short* __restrict__ x_bf,     // [512][64][256] bf16
    const short* __restrict__ w_pack,   // [2][1024][512] bf16, row p=jc*4+gate
    const float* __restrict__ bias_p,   // [2][1024]
    short* __restrict__ h_buf,          // [2][2][64*256] bf16 (chain, parity)
    int* __restrict__ flags,            // [2][64] ints, use [ch*64+g]
    float* __restrict__ out)            // [64][512]
{
  const int ch   = blockIdx.x >> 2;
  const int g    = blockIdx.x & 3;
  const int tid  = threadIdx.x;
  const int wave = tid >> 6;
  const int lane = tid & 63;
  const int l15  = lane & 15;
  const int l4   = lane >> 4;
  const int colbase = g * 64 + wave * 8;   // first h-col owned by this wave

  const short* wp = w_pack + (long)ch * 1024 * 512;

  // A-fragments (weights), register-resident: 2 M-tiles x 16 K-steps x 16B
  short8 a[2][16];
#pragma unroll
  for (int mt = 0; mt < 2; ++mt)
#pragma unroll
    for (int ks = 0; ks < 16; ++ks) {
      int p  = colbase * 4 + mt * 16 + l15;
      int k0 = ks * 32 + l4 * 8;
      a[mt][ks] = *(const short8*)(wp + (long)p * 512 + k0);
    }

  // bias quad per M-tile: rows jc*4 .. jc*4+3 == (i,f,g,o)
  f32x4 bias4[2];
#pragma unroll
  for (int mt = 0; mt < 2; ++mt) {
    int jc = colbase + mt * 4 + l4;
    bias4[mt] = *(const f32x4*)(bias_p + ch * 1024 + jc * 4);
  }

  float cstate[2][4];
  float hmax[2][4];
#pragma unroll
  for (int mt = 0; mt < 2; ++mt)
#pragma unroll
    for (int n = 0; n < 4; ++n) { cstate[mt][n] = 0.f; hmax[mt][n] = -2.f; }

  short* hb0 = h_buf + (long)ch * 2 * B_ * H_;
  int* myflags = flags + ch * 64;

  for (int t = 0; t < NSTEP; ++t) {
    int tok;
    if (ch == 0) tok = (t + 1) >> 1;
    else         tok = (t == NSTEP - 1) ? (S_ - 1) : ((t & 1) ? (t >> 1) : (t >> 1) + 1);

    const short* xr = x_bf + (long)tok * B_ * E_;
    const short* hr = hb0 + ((t + 1) & 1) * (B_ * H_);
    short*       hw = hb0 + (t & 1) * (B_ * H_);

    f32x4 acc[2][4];
#pragma unroll
    for (int mt = 0; mt < 2; ++mt)
#pragma unroll
      for (int n = 0; n < 4; ++n) acc[mt][n] = (f32x4){0.f, 0.f, 0.f, 0.f};

    // ---- x-part (K-steps 0..7) has no dependence on h_{t-1}: do it before the wait ----
#pragma unroll
    for (int ks = 0; ks < 8; ++ks) {
      int k0 = ks * 32 + l4 * 8;
#pragma unroll
      for (int n = 0; n < 4; ++n) {
        int b = n * 16 + l15;
        short8 bf = *(const short8*)(xr + (long)b * E_ + k0);
        acc[0][n] = __builtin_amdgcn_mfma_f32_16x16x32_bf16(a[0][ks], bf, acc[0][n], 0, 0, 0);
        acc[1][n] = __builtin_amdgcn_mfma_f32_16x16x32_bf16(a[1][ks], bf, acc[1][n], 0, 0, 0);
      }
    }

    // ---- wait until all 4 groups of this chain published h_{t-1} ----
    if (tid < 4) {
      while (__hip_atomic_load(&myflags[tid], __ATOMIC_ACQUIRE, __HIP_MEMORY_SCOPE_AGENT) < t) {}
    }
    __syncthreads();

    // ---- h-part (K-steps 8..15) ----
#pragma unroll
    for (int ks = 8; ks < 16; ++ks) {
      int k0 = ks * 32 + l4 * 8 - 256;
#pragma unroll
      for (int n = 0; n < 4; ++n) {
        int b = n * 16 + l15;
        short8 bf = *(const short8*)(hr + (long)b * H_ + k0);
        acc[0][n] = __builtin_amdgcn_mfma_f32_16x16x32_bf16(a[0][ks], bf, acc[0][n], 0, 0, 0);
        acc[1][n] = __builtin_amdgcn_mfma_f32_16x16x32_bf16(a[1][ks], bf, acc[1][n], 0, 0, 0);
      }
    }

    // ---- gates / state update / h write ----
#pragma unroll
    for (int mt = 0; mt < 2; ++mt) {
      int jc = colbase + mt * 4 + l4;
#pragma unroll
      for (int n = 0; n < 4; ++n) {
        int b = n * 16 + l15;
        float zi = acc[mt][n][0] + bias4[mt][0];
        float zf = acc[mt][n][1] + bias4[mt][1];
        float zg = acc[mt][n][2] + bias4[mt][2];
        float zo = acc[mt][n][3] + bias4[mt][3];
        float cc = cstate[mt][n];
        cc = sigm(zf) * cc + sigm(zi) * tanh_(zg);
        float hh = sigm(zo) * tanh_(cc);
        cstate[mt][n] = cc;
        hmax[mt][n] = fmaxf(hmax[mt][n], hh);
        hw[(long)b * H_ + jc] = f2bf(hh);
      }
    }

    __syncthreads();  // all waves' h stores drained (per-wave vmcnt(0) before s_barrier)
    if (tid == 0) {
      __hip_atomic_store(&myflags[g], t + 1, __ATOMIC_RELEASE, __HIP_MEMORY_SCOPE_AGENT);
    }
  }

  // ---- final: write running maxes ----
#pragma unroll
  for (int mt = 0; mt < 2; ++mt) {
    int jc = colbase + mt * 4 + l4;
#pragma unroll
    for (int n = 0; n < 4; ++n) {
      int b = n * 16 + l15;
      out[(long)b * (2 * H_) + ch * H_ + jc] = hmax[mt][n];
    }
  }
}

extern "C" void kernel_launch(void* const* d_in, const int* in_sizes, int n_in,
                              void* d_out, int out_size, void* d_ws, size_t ws_size,
                              hipStream_t stream) {
  const float* x     = (const float*)d_in[0];
  const float* wih_f = (const float*)d_in[1];
  const float* whh_f = (const float*)d_in[2];
  const float* bih_f = (const float*)d_in[3];
  const float* bhh_f = (const float*)d_in[4];
  const float* wih_b = (const float*)d_in[5];
  const float* whh_b = (const float*)d_in[6];
  const float* bih_b = (const float*)d_in[7];
  const float* bhh_b = (const float*)d_in[8];

  char* ws = (char*)d_ws;
  short* x_bf   = (short*)(ws);                 // 16,777,216 B
  short* w_pack = (short*)(ws + 16777216);      //  2,097,152 B
  float* bias_p = (float*)(ws + 18874368);      //      8,192 B
  short* h_buf  = (short*)(ws + 18882560);      //    131,072 B
  int*   flags  = (int*)  (ws + 19013632);      //        512 B
  if (ws_size < 19014144) return;

  hipMemsetAsync(ws + 18882560, 0, 131584, stream);  // zero h bufs + flags each call

  prep_kernel<<<2048, 256, 0, stream>>>(x, wih_f, whh_f, bih_f, bhh_f,
                                        wih_b, whh_b, bih_b, bhh_b,
                                        x_bf, w_pack, bias_p);
  lstm_seq<<<8, 512, 0, stream>>>(x_bf, w_pack, bias_p, h_buf, flags, (float*)d_out);
}

// Round 2
// 11678.313 us; speedup vs baseline: 1.5502x; 1.5502x over previous
//
#include <hip/hip_runtime.h>

typedef __attribute__((ext_vector_type(8))) short short8;
typedef __attribute__((ext_vector_type(4))) float f32x4;
typedef __attribute__((ext_vector_type(4))) unsigned short u16x4;

#define S_ 512
#define B_ 64
#define E_ 256
#define H_ 256
#define NSTEP 1023  // 2*S - 1 sequential cell steps per chain

// ---------- helpers ----------
__device__ __forceinline__ unsigned short f2bf(float f) {
  unsigned u = __builtin_bit_cast(unsigned, f);
  return (unsigned short)((u + 0x7fffu + ((u >> 16) & 1u)) >> 16);  // RNE
}
__device__ __forceinline__ float bf2f(unsigned short h) {
  unsigned u = ((unsigned)h) << 16;
  return __builtin_bit_cast(float, u);
}
__device__ __forceinline__ float sigm(float x) { return 1.f / (1.f + __expf(-x)); }
__device__ __forceinline__ float tanh_(float x) {
  x = fminf(fmaxf(x, -15.f), 15.f);
  float e = __expf(-2.f * x);
  return (1.f - e) / (1.f + e);
}

// ---------- prep: cast x to bf16; pack Wih and Whh rows in p=jc*4+gate order; combine biases ----------
// E == H == 256, so wx and wh have identical shapes [2][1024][256].
__global__ __launch_bounds__(256) void prep2(
    const float* __restrict__ x,
    const float* __restrict__ wih_f, const float* __restrict__ whh_f,
    const float* __restrict__ bih_f, const float* __restrict__ bhh_f,
    const float* __restrict__ wih_b, const float* __restrict__ whh_b,
    const float* __restrict__ bih_b, const float* __restrict__ bhh_b,
    short* __restrict__ x_bf, short* __restrict__ wx, short* __restrict__ wh,
    float* __restrict__ bias_p)
{
  long i0 = (long)blockIdx.x * blockDim.x + threadIdx.x;
  long stride = (long)gridDim.x * blockDim.x;
  const long NX = (long)S_ * B_ * E_;     // 8,388,608
  const long NW = 2L * 1024 * 256;        // 524,288 (per weight matrix)
  const long NB = 2L * 1024;

  for (long i = i0; i < NX; i += stride) x_bf[i] = (short)f2bf(x[i]);

  for (long i = i0; i < NW; i += stride) {
    int ch  = (int)(i >> 18);        // 1024*256 = 2^18
    int rem = (int)(i & 262143);
    int p   = rem >> 8;              // packed row 0..1023
    int k   = rem & 255;
    int jc  = p >> 2, g = p & 3;
    long j  = (long)(g * 256 + jc);  // original gate row
    wx[i] = (short)f2bf((ch ? wih_b : wih_f)[j * 256 + k]);
    wh[i] = (short)f2bf((ch ? whh_b : whh_f)[j * 256 + k]);
  }

  for (long i = i0; i < NB; i += stride) {
    int ch = (int)(i >> 10);
    int p  = (int)(i & 1023);
    int jc = p >> 2, g = p & 3;
    int j  = g * 256 + jc;
    bias_p[i] = ch ? (bih_b[j] + bhh_b[j]) : (bih_f[j] + bhh_f[j]);
  }
}

// ---------- xz precompute: xz[ch][t][jc][b][g] = (Wih x_t)[p=jc*4+g][b] ----------
// grid = 1024 blocks (ch,t), 512 threads (8 waves). Each wave: 8 M-tiles x 4 N-tiles.
template<bool F32>
__global__ __launch_bounds__(512) void xz_gemm(
    const short* __restrict__ x_bf, const short* __restrict__ wx,
    void* __restrict__ xz)
{
  const int bid = blockIdx.x;
  const int ch = bid >> 9, t = bid & 511;
  const int tid = threadIdx.x;
  const int wave = tid >> 6, lane = tid & 63;
  const int l15 = lane & 15, l4 = lane >> 4;

  const short* W = wx + (long)ch * 1024 * 256;
  const short* X = x_bf + (long)t * B_ * E_;

  f32x4 acc[8][4];
#pragma unroll
  for (int mt = 0; mt < 8; ++mt)
#pragma unroll
    for (int nt = 0; nt < 4; ++nt) acc[mt][nt] = (f32x4){0.f, 0.f, 0.f, 0.f};

#pragma unroll
  for (int ks = 0; ks < 8; ++ks) {
    int k0 = ks * 32 + l4 * 8;
    short8 bfr[4];
#pragma unroll
    for (int nt = 0; nt < 4; ++nt)
      bfr[nt] = *(const short8*)(X + (long)(nt * 16 + l15) * E_ + k0);
#pragma unroll
    for (int mt = 0; mt < 8; ++mt) {
      int p = (wave * 8 + mt) * 16 + l15;
      short8 af = *(const short8*)(W + (long)p * 256 + k0);
#pragma unroll
      for (int nt = 0; nt < 4; ++nt)
        acc[mt][nt] = __builtin_amdgcn_mfma_f32_16x16x32_bf16(af, bfr[nt], acc[mt][nt], 0, 0, 0);
    }
  }

#pragma unroll
  for (int mt = 0; mt < 8; ++mt) {
    int jc = (wave * 8 + mt) * 4 + l4;
#pragma unroll
    for (int nt = 0; nt < 4; ++nt) {
      int b = nt * 16 + l15;
      long base = ((((long)ch * 512 + t) * 256 + jc) * 64 + b) * 4;
      if (F32) {
        *(f32x4*)((float*)xz + base) = acc[mt][nt];
      } else {
        u16x4 v;
#pragma unroll
        for (int g = 0; g < 4; ++g) v[g] = f2bf(acc[mt][nt][g]);
        *(u16x4*)((short*)xz + base) = v;
      }
    }
  }
}

// ---------- sequential bi-chain LSTM, batch-split: zero cross-block sync ----------
// grid = 8 blocks: ch = bid>>2, batch-slice bs = bid&3 (16 cols each). 1024 threads (16 waves).
// Each block keeps its h-state in LDS; Whh fully register-resident per wave (4 M-tiles x 8 ks).
// MODE: 0 = fused x (K=512, no xz), 1 = xz bf16, 2 = xz fp32.
template<int MODE>
__global__ __launch_bounds__(1024) void lstm2(
    const short* __restrict__ x_bf, const short* __restrict__ wx,
    const short* __restrict__ wh, const float* __restrict__ bias_p,
    const void* __restrict__ xz, float* __restrict__ out)
{
  const int ch = blockIdx.x >> 2;
  const int bs = blockIdx.x & 3;
  const int tid = threadIdx.x;
  const int wave = tid >> 6, lane = tid & 63;
  const int l15 = lane & 15, l4 = lane >> 4;
  const int bloc = l15;                // local batch col (0..15)
  const int bglob = bs * 16 + l15;     // global batch col

  const short* whc = wh + (long)ch * 1024 * 256;
  const short* wxc = wx + (long)ch * 1024 * 256;

  // register-resident A-fragments of Whh: wave owns packed rows [wave*64, wave*64+64)
  short8 ah[4][8];
#pragma unroll
  for (int mt = 0; mt < 4; ++mt)
#pragma unroll
    for (int ks = 0; ks < 8; ++ks) {
      int p = wave * 64 + mt * 16 + l15;
      int k0 = ks * 32 + l4 * 8;
      ah[mt][ks] = *(const short8*)(whc + (long)p * 256 + k0);
    }

  short8 ax[4][8];
  if (MODE == 0) {
#pragma unroll
    for (int mt = 0; mt < 4; ++mt)
#pragma unroll
      for (int ks = 0; ks < 8; ++ks) {
        int p = wave * 64 + mt * 16 + l15;
        int k0 = ks * 32 + l4 * 8;
        ax[mt][ks] = *(const short8*)(wxc + (long)p * 256 + k0);
      }
  }

  f32x4 bias4[4];
#pragma unroll
  for (int mt = 0; mt < 4; ++mt) {
    int jc = wave * 16 + mt * 4 + l4;
    bias4[mt] = *(const f32x4*)(bias_p + ch * 1024 + jc * 4);
  }

  float cst[4], hmax[4];
#pragma unroll
  for (int mt = 0; mt < 4; ++mt) { cst[mt] = 0.f; hmax[mt] = -2.f; }

  __shared__ short hlds[2][16][256];   // [parity][local b][k, XOR-swizzled]
  for (int i = tid; i < 2 * 16 * 256; i += 1024) ((short*)hlds)[i] = 0;
  __syncthreads();

  for (int t = 0; t < NSTEP; ++t) {
    int tok;
    if (ch == 0) tok = (t + 1) >> 1;
    else         tok = (t == NSTEP - 1) ? (S_ - 1) : ((t & 1) ? (t >> 1) : (t >> 1) + 1);

    // prefetch xz addends (independent of h -> latency hidden under MFMAs)
    f32x4 xzv[4];
    if (MODE == 1) {
#pragma unroll
      for (int mt = 0; mt < 4; ++mt) {
        int jc = wave * 16 + mt * 4 + l4;
        long base = ((((long)ch * 512 + tok) * 256 + jc) * 64 + bglob) * 4;
        u16x4 v = *(const u16x4*)((const short*)xz + base);
#pragma unroll
        for (int g = 0; g < 4; ++g) xzv[mt][g] = bf2f(v[g]);
      }
    } else if (MODE == 2) {
#pragma unroll
      for (int mt = 0; mt < 4; ++mt) {
        int jc = wave * 16 + mt * 4 + l4;
        long base = ((((long)ch * 512 + tok) * 256 + jc) * 64 + bglob) * 4;
        xzv[mt] = *(const f32x4*)((const float*)xz + base);
      }
    }

    f32x4 acc[4];
#pragma unroll
    for (int mt = 0; mt < 4; ++mt) acc[mt] = (f32x4){0.f, 0.f, 0.f, 0.f};

    if (MODE == 0) {
      const short* xr = x_bf + (long)tok * B_ * E_;
#pragma unroll
      for (int ks = 0; ks < 8; ++ks) {
        int k0 = ks * 32 + l4 * 8;
        short8 bfr = *(const short8*)(xr + (long)bglob * E_ + k0);
#pragma unroll
        for (int mt = 0; mt < 4; ++mt)
          acc[mt] = __builtin_amdgcn_mfma_f32_16x16x32_bf16(ax[mt][ks], bfr, acc[mt], 0, 0, 0);
      }
    }

    // recurrent part: h_{t-1} from LDS parity (t+1)&1
    const int par = (t + 1) & 1;
#pragma unroll
    for (int ks = 0; ks < 8; ++ks) {
      int k0 = (ks * 32 + l4 * 8) ^ ((bloc & 7) << 3);   // XOR swizzle, keeps 8-contiguity
      short8 hfr = *(const short8*)(&hlds[par][bloc][k0]);
#pragma unroll
      for (int mt = 0; mt < 4; ++mt)
        acc[mt] = __builtin_amdgcn_mfma_f32_16x16x32_bf16(ah[mt][ks], hfr, acc[mt], 0, 0, 0);
    }

    // gates: acc[mt][g] is gate g (i,f,g,o) of h-col jc = wave*16+mt*4+l4, batch bglob
#pragma unroll
    for (int mt = 0; mt < 4; ++mt) {
      int jc = wave * 16 + mt * 4 + l4;
      float zi = acc[mt][0] + bias4[mt][0];
      float zf = acc[mt][1] + bias4[mt][1];
      float zg = acc[mt][2] + bias4[mt][2];
      float zo = acc[mt][3] + bias4[mt][3];
      if (MODE > 0) {
        zi += xzv[mt][0]; zf += xzv[mt][1]; zg += xzv[mt][2]; zo += xzv[mt][3];
      }
      float cc = cst[mt];
      cc = sigm(zf) * cc + sigm(zi) * tanh_(zg);
      float hh = sigm(zo) * tanh_(cc);
      cst[mt] = cc;
      hmax[mt] = fmaxf(hmax[mt], hh);
      hlds[t & 1][bloc][jc ^ ((bloc & 7) << 3)] = (short)f2bf(hh);
    }

    __syncthreads();
  }

#pragma unroll
  for (int mt = 0; mt < 4; ++mt) {
    int jc = wave * 16 + mt * 4 + l4;
    out[(long)bglob * (2 * H_) + ch * H_ + jc] = hmax[mt];
  }
}

extern "C" void kernel_launch(void* const* d_in, const int* in_sizes, int n_in,
                              void* d_out, int out_size, void* d_ws, size_t ws_size,
                              hipStream_t stream) {
  const float* x     = (const float*)d_in[0];
  const float* wih_f = (const float*)d_in[1];
  const float* whh_f = (const float*)d_in[2];
  const float* bih_f = (const float*)d_in[3];
  const float* bhh_f = (const float*)d_in[4];
  const float* wih_b = (const float*)d_in[5];
  const float* whh_b = (const float*)d_in[6];
  const float* bih_b = (const float*)d_in[7];
  const float* bhh_b = (const float*)d_in[8];

  char* ws = (char*)d_ws;
  short* x_bf   = (short*)(ws);                 // 16,777,216 B
  short* wx     = (short*)(ws + 16777216);      //  1,048,576 B
  short* wh     = (short*)(ws + 17825792);      //  1,048,576 B
  float* bias_p = (float*)(ws + 18874368);      //      8,192 B
  void*  xz     = (void*) (ws + 18882560);      // xz: fp32 268,435,456 B or bf16 134,217,728 B

  const size_t NEED_F32 = 18882560UL + 268435456UL;   // 287,318,016
  const size_t NEED_BF  = 18882560UL + 134217728UL;   // 153,100,288
  if (ws_size < 18882560UL) return;

  prep2<<<2048, 256, 0, stream>>>(x, wih_f, whh_f, bih_f, bhh_f,
                                  wih_b, whh_b, bih_b, bhh_b,
                                  x_bf, wx, wh, bias_p);

  float* outp = (float*)d_out;
  if (ws_size >= NEED_F32) {
    xz_gemm<true><<<1024, 512, 0, stream>>>(x_bf, wx, xz);
    lstm2<2><<<8, 1024, 0, stream>>>(x_bf, wx, wh, bias_p, xz, outp);
  } else if (ws_size >= NEED_BF) {
    xz_gemm<false><<<1024, 512, 0, stream>>>(x_bf, wx, xz);
    lstm2<1><<<8, 1024, 0, stream>>>(x_bf, wx, wh, bias_p, xz, outp);
  } else {
    lstm2<0><<<8, 1024, 0, stream>>>(x_bf, wx, wh, bias_p, xz, outp);
  }
}

// Round 3
// 6748.115 us; speedup vs baseline: 2.6827x; 1.7306x over previous
//
#include <hip/hip_runtime.h>

typedef __attribute__((ext_vector_type(8))) short short8;
typedef __attribute__((ext_vector_type(4))) float f32x4;
typedef __attribute__((ext_vector_type(4))) unsigned short u16x4;
typedef __attribute__((ext_vector_type(8))) unsigned short u16x8;

#define S_ 512
#define B_ 64
#define E_ 256
#define H_ 256
#define NSTEP 1023  // 2*S - 1 sequential cell steps per chain

// ---------- helpers ----------
__device__ __forceinline__ unsigned short f2bf(float f) {
  unsigned u = __builtin_bit_cast(unsigned, f);
  return (unsigned short)((u + 0x7fffu + ((u >> 16) & 1u)) >> 16);  // RNE
}
__device__ __forceinline__ float bf2f(unsigned short h) {
  unsigned u = ((unsigned)h) << 16;
  return __builtin_bit_cast(float, u);
}
__device__ __forceinline__ float sigm(float x) { return 1.f / (1.f + __expf(-x)); }
__device__ __forceinline__ float tanh_(float x) {
  x = fminf(fmaxf(x, -15.f), 15.f);
  float e = __expf(-2.f * x);
  return (1.f - e) / (1.f + e);
}

// ---------- prep ----------
// x -> bf16; wx packed rows p=jc*4+gate, natural columns (K = E);
// wh packed rows p=jc*4+gate, PERMUTED columns: stored col k holds original col
// orig(k) = (k&~15) | ((k&3)<<2) | ((k>>2)&3)   (so h can be written contiguously);
// bias combined.
__global__ __launch_bounds__(256) void prep3(
    const float* __restrict__ x,
    const float* __restrict__ wih_f, const float* __restrict__ whh_f,
    const float* __restrict__ bih_f, const float* __restrict__ bhh_f,
    const float* __restrict__ wih_b, const float* __restrict__ whh_b,
    const float* __restrict__ bih_b, const float* __restrict__ bhh_b,
    short* __restrict__ x_bf, short* __restrict__ wx, short* __restrict__ wh,
    float* __restrict__ bias_p)
{
  long i0 = (long)blockIdx.x * blockDim.x + threadIdx.x;
  long stride = (long)gridDim.x * blockDim.x;
  const long NX = (long)S_ * B_ * E_;
  const long NW = 2L * 1024 * 256;
  const long NB = 2L * 1024;

  for (long i = i0; i < NX; i += stride) x_bf[i] = (short)f2bf(x[i]);

  for (long i = i0; i < NW; i += stride) {
    int ch  = (int)(i >> 18);
    int rem = (int)(i & 262143);
    int p   = rem >> 8;              // packed row 0..1023
    int k   = rem & 255;
    int jc  = p >> 2, g = p & 3;
    long j  = (long)(g * 256 + jc);  // original gate row
    int ko  = (k & ~15) | ((k & 3) << 2) | ((k >> 2) & 3);
    wx[i] = (short)f2bf((ch ? wih_b : wih_f)[j * 256 + k]);
    wh[i] = (short)f2bf((ch ? whh_b : whh_f)[j * 256 + ko]);
  }

  for (long i = i0; i < NB; i += stride) {
    int ch = (int)(i >> 10);
    int p  = (int)(i & 1023);
    int jc = p >> 2, g = p & 3;
    int j  = g * 256 + jc;
    bias_p[i] = ch ? (bih_b[j] + bhh_b[j]) : (bih_f[j] + bhh_f[j]);
  }
}

// ---------- xz precompute (bias folded), bf16 ----------
// layout: xz[ch][t][wl 16][b 64][ll 4][mt 4][g 4]  with jc = wl*16 + mt*4 + ll
__global__ __launch_bounds__(512, 2) void xz_gemm3(
    const short* __restrict__ x_bf, const short* __restrict__ wx,
    const float* __restrict__ bias_p, short* __restrict__ xz)
{
  const int bid = blockIdx.x;
  const int ch = bid >> 9, t = bid & 511;
  const int tid = threadIdx.x;
  const int wave = tid >> 6, lane = tid & 63;
  const int l15 = lane & 15, l4 = lane >> 4;

  const short* W = wx + (long)ch * 1024 * 256;
  const short* X = x_bf + (long)t * B_ * E_;

  f32x4 acc[8][4];
#pragma unroll
  for (int mt = 0; mt < 8; ++mt)
#pragma unroll
    for (int nt = 0; nt < 4; ++nt) acc[mt][nt] = (f32x4){0.f, 0.f, 0.f, 0.f};

#pragma unroll
  for (int ks = 0; ks < 8; ++ks) {
    int k0 = ks * 32 + l4 * 8;
    short8 bfr[4];
#pragma unroll
    for (int nt = 0; nt < 4; ++nt)
      bfr[nt] = *(const short8*)(X + (long)(nt * 16 + l15) * E_ + k0);
#pragma unroll
    for (int mt = 0; mt < 8; ++mt) {
      int p = (wave * 8 + mt) * 16 + l15;
      short8 af = *(const short8*)(W + (long)p * 256 + k0);
#pragma unroll
      for (int nt = 0; nt < 4; ++nt)
        acc[mt][nt] = __builtin_amdgcn_mfma_f32_16x16x32_bf16(af, bfr[nt], acc[mt][nt], 0, 0, 0);
    }
  }

#pragma unroll
  for (int mt = 0; mt < 8; ++mt) {
    int jc = (wave * 8 + mt) * 4 + l4;
    int wl = jc >> 4, ml = (jc >> 2) & 3, ll = jc & 3;
    f32x4 b4 = *(const f32x4*)(bias_p + ch * 1024 + jc * 4);
#pragma unroll
    for (int nt = 0; nt < 4; ++nt) {
      int b = nt * 16 + l15;
      u16x4 v;
#pragma unroll
      for (int g = 0; g < 4; ++g) v[g] = f2bf(acc[mt][nt][g] + b4[g]);
      long off = ((((long)ch * 512 + t) * 16 + wl) * 64 + b) * 64 + ll * 16 + ml * 4;
      *(u16x4*)(xz + off) = v;
    }
  }
}

// ---------- sequential bi-chain LSTM ----------
// grid 8: ch = bid>>2, batch-slice bs = bid&3 (16 cols). 1024 threads (16 waves), 1 block/CU.
// Whh: 3/4 register-resident (96 VGPR/wave), 1/4 in LDS (128KB, XOR-swizzled).
// h state double-buffered in LDS (16KB, swizzled, K-permuted so writes are b64-contiguous).
// MODE 1: xz precomputed bf16 (bias folded). MODE 0: fused fallback (streams Wih from L2).
template<int MODE>
__global__ __launch_bounds__(1024, 4) void lstm3(
    const short* __restrict__ x_bf, const short* __restrict__ wx,
    const short* __restrict__ wh, const float* __restrict__ bias_p,
    const short* __restrict__ xz, float* __restrict__ out)
{
  const int ch = blockIdx.x >> 2;
  const int bs = blockIdx.x & 3;
  const int tid = threadIdx.x;
  const int wave = tid >> 6, lane = tid & 63;
  const int l15 = lane & 15, l4 = lane >> 4;
  const int bloc = l15;                // local batch col
  const int bglob = bs * 16 + l15;     // global batch col

  __shared__ short w_lds[16 * 16 * 256];  // 128 KB: per wave rows wave*64+48..63, swizzled
  __shared__ short h_lds[2 * 16 * 256];   // 16 KB: [parity][bloc][256 K-permuted], swizzled

  const short* whc = wh + (long)ch * 1024 * 256;
  const short* wxc = wx + (long)ch * 1024 * 256;

  // ---- init: stage 4th M-tile of Whh into LDS (swizzled), zero h ----
  {
    char* wl = (char*)w_lds;
#pragma unroll
    for (int c = 0; c < 8; ++c) {
      int chunk = c * 64 + lane;           // 0..511 within wave
      int row = chunk >> 5;                // 0..15
      int c16 = chunk & 31;                // 16B column
      short8 v = *(const short8*)(whc + (long)(wave * 64 + 48 + row) * 256 + c16 * 8);
      int boff = wave * 8192 + row * 512 + ((c16 * 16) ^ ((row & 7) << 4));
      *(short8*)(wl + boff) = v;
    }
    for (int i = tid; i < 2 * 16 * 256; i += 1024) h_lds[i] = 0;
  }

  // ---- register A-fragments: M-tiles 0..2 (rows wave*64 .. +47) ----
  short8 ah[3][8];
#pragma unroll
  for (int mt = 0; mt < 3; ++mt)
#pragma unroll
    for (int ks = 0; ks < 8; ++ks) {
      int p = wave * 64 + mt * 16 + l15;
      int k0 = ks * 32 + l4 * 8;
      ah[mt][ks] = *(const short8*)(whc + (long)p * 256 + k0);
    }

  f32x4 bias4v[4];
  if (MODE == 0) {
#pragma unroll
    for (int mt = 0; mt < 4; ++mt) {
      int jc = wave * 16 + mt * 4 + l4;
      bias4v[mt] = *(const f32x4*)(bias_p + ch * 1024 + jc * 4);
    }
  }

  float cst[4], hmax[4];
#pragma unroll
  for (int mt = 0; mt < 4; ++mt) { cst[mt] = 0.f; hmax[mt] = -2.f; }

  __syncthreads();

  const char* hlr = (const char*)h_lds;
  const char* wlr = (const char*)w_lds;
  char* hlw = (char*)h_lds;
  const int swzb = (bloc & 7) << 4;
  const int wboff = wave * 8192 + l15 * 512;   // w_lds per-lane row base
  const int q0b = (wave * 16 + l4 * 4) * 2;    // h-write byte offset (pre-swizzle)

  for (int t = 0; t < NSTEP; ++t) {
    int tok;
    if (ch == 0) tok = (t + 1) >> 1;
    else         tok = (t == NSTEP - 1) ? (S_ - 1) : ((t & 1) ? (t >> 1) : (t >> 1) + 1);

    // prefetch this thread's 16 xz addends (32B contiguous; wave covers 2KB dense)
    u16x8 xza, xzb;
    if (MODE == 1) {
      const short* xp = xz + (((((long)ch * 512 + tok) * 16 + wave) * 64 + bglob) * 64 + l4 * 16);
      xza = *(const u16x8*)(xp);
      xzb = *(const u16x8*)(xp + 8);
    }

    f32x4 acc[4];
#pragma unroll
    for (int mt = 0; mt < 4; ++mt) acc[mt] = (f32x4){0.f, 0.f, 0.f, 0.f};

    if (MODE == 0) {  // fused x-part: stream Wih fragments from L2
      const short* xr = x_bf + ((long)tok * B_ + bglob) * E_;
#pragma unroll
      for (int ks = 0; ks < 8; ++ks) {
        int k0 = ks * 32 + l4 * 8;
        short8 bx = *(const short8*)(xr + k0);
#pragma unroll
        for (int mt = 0; mt < 4; ++mt) {
          short8 axf = *(const short8*)(wxc + (long)(wave * 64 + mt * 16 + l15) * 256 + k0);
          acc[mt] = __builtin_amdgcn_mfma_f32_16x16x32_bf16(axf, bx, acc[mt], 0, 0, 0);
        }
      }
    }

    // recurrent part
    const int hbase = (((t + 1) & 1) * 8192) + bloc * 512;
#pragma unroll
    for (int ks = 0; ks < 8; ++ks) {
      int koff = ks * 64 + l4 * 16;
      short8 hfr = *(const short8*)(hlr + hbase + (koff ^ swzb));
      acc[0] = __builtin_amdgcn_mfma_f32_16x16x32_bf16(ah[0][ks], hfr, acc[0], 0, 0, 0);
      acc[1] = __builtin_amdgcn_mfma_f32_16x16x32_bf16(ah[1][ks], hfr, acc[1], 0, 0, 0);
      acc[2] = __builtin_amdgcn_mfma_f32_16x16x32_bf16(ah[2][ks], hfr, acc[2], 0, 0, 0);
      short8 wfr = *(const short8*)(wlr + wboff + (koff ^ ((l15 & 7) << 4)));
      acc[3] = __builtin_amdgcn_mfma_f32_16x16x32_bf16(wfr, hfr, acc[3], 0, 0, 0);
    }

    // gates + state + h write (single b64, K-permuted layout)
    unsigned short hv[4];
#pragma unroll
    for (int mt = 0; mt < 4; ++mt) {
      float zi = acc[mt][0], zf = acc[mt][1], zg = acc[mt][2], zo = acc[mt][3];
      if (MODE == 1) {
        const int o = (mt & 1) * 4;
        if (mt < 2) { zi += bf2f(xza[o]); zf += bf2f(xza[o + 1]); zg += bf2f(xza[o + 2]); zo += bf2f(xza[o + 3]); }
        else        { zi += bf2f(xzb[o]); zf += bf2f(xzb[o + 1]); zg += bf2f(xzb[o + 2]); zo += bf2f(xzb[o + 3]); }
      } else {
        zi += bias4v[mt][0]; zf += bias4v[mt][1]; zg += bias4v[mt][2]; zo += bias4v[mt][3];
      }
      float cc = cst[mt];
      cc = sigm(zf) * cc + sigm(zi) * tanh_(zg);
      float hh = sigm(zo) * tanh_(cc);
      cst[mt] = cc;
      hmax[mt] = fmaxf(hmax[mt], hh);
      hv[mt] = f2bf(hh);
    }
    {
      u16x4 hw4 = {hv[0], hv[1], hv[2], hv[3]};
      int wb = ((t & 1) * 8192) + bloc * 512 + (q0b ^ swzb);
      *(u16x4*)(hlw + wb) = hw4;
    }

    __syncthreads();
  }

#pragma unroll
  for (int mt = 0; mt < 4; ++mt) {
    int jc = wave * 16 + mt * 4 + l4;
    out[(long)bglob * (2 * H_) + ch * H_ + jc] = hmax[mt];
  }
}

extern "C" void kernel_launch(void* const* d_in, const int* in_sizes, int n_in,
                              void* d_out, int out_size, void* d_ws, size_t ws_size,
                              hipStream_t stream) {
  const float* x     = (const float*)d_in[0];
  const float* wih_f = (const float*)d_in[1];
  const float* whh_f = (const float*)d_in[2];
  const float* bih_f = (const float*)d_in[3];
  const float* bhh_f = (const float*)d_in[4];
  const float* wih_b = (const float*)d_in[5];
  const float* whh_b = (const float*)d_in[6];
  const float* bih_b = (const float*)d_in[7];
  const float* bhh_b = (const float*)d_in[8];

  char* ws = (char*)d_ws;
  short* x_bf   = (short*)(ws);                 // 16,777,216 B
  short* wx     = (short*)(ws + 16777216);      //  1,048,576 B
  short* wh     = (short*)(ws + 17825792);      //  1,048,576 B
  float* bias_p = (float*)(ws + 18874368);      //      8,192 B
  short* xz     = (short*)(ws + 18882560);      // 134,217,728 B (bf16)

  const size_t NEED_XZ = 18882560UL + 134217728UL;   // 153,100,288
  if (ws_size < 18882560UL) return;

  prep3<<<2048, 256, 0, stream>>>(x, wih_f, whh_f, bih_f, bhh_f,
                                  wih_b, whh_b, bih_b, bhh_b,
                                  x_bf, wx, wh, bias_p);

  float* outp = (float*)d_out;
  if (ws_size >= NEED_XZ) {
    xz_gemm3<<<1024, 512, 0, stream>>>(x_bf, wx, bias_p, xz);
    lstm3<1><<<8, 1024, 0, stream>>>(x_bf, wx, wh, bias_p, xz, outp);
  } else {
    lstm3<0><<<8, 1024, 0, stream>>>(x_bf, wx, wh, bias_p, xz, outp);
  }
}

// Round 4
// 6732.441 us; speedup vs baseline: 2.6890x; 1.0023x over previous
//
#include <hip/hip_runtime.h>

typedef __attribute__((ext_vector_type(8))) short short8;
typedef __attribute__((ext_vector_type(4))) float f32x4;
typedef __attribute__((ext_vector_type(4))) unsigned short u16x4;
typedef __attribute__((ext_vector_type(8))) unsigned short u16x8;

#define S_ 512
#define B_ 64
#define E_ 256
#define H_ 256
#define NSTEP 1023  // 2*S - 1 sequential cell steps per chain

// ---------- helpers ----------
__device__ __forceinline__ unsigned short f2bf(float f) {
  unsigned u = __builtin_bit_cast(unsigned, f);
  return (unsigned short)((u + 0x7fffu + ((u >> 16) & 1u)) >> 16);  // RNE
}
__device__ __forceinline__ float bf2f(unsigned short h) {
  unsigned u = ((unsigned)h) << 16;
  return __builtin_bit_cast(float, u);
}
__device__ __forceinline__ float sigm(float x) { return 1.f / (1.f + __expf(-x)); }
__device__ __forceinline__ float tanh_(float x) {
  x = fminf(fmaxf(x, -15.f), 15.f);
  float e = __expf(-2.f * x);
  return (1.f - e) / (1.f + e);
}

// ---------- prep ----------
// x -> bf16; wx packed rows p=jc*4+gate, natural cols; wh packed rows, PERMUTED cols:
// stored col k holds orig col (k&~15)|((k&3)<<2)|((k>>2)&3); bias combined.
__global__ __launch_bounds__(256) void prep3(
    const float* __restrict__ x,
    const float* __restrict__ wih_f, const float* __restrict__ whh_f,
    const float* __restrict__ bih_f, const float* __restrict__ bhh_f,
    const float* __restrict__ wih_b, const float* __restrict__ whh_b,
    const float* __restrict__ bih_b, const float* __restrict__ bhh_b,
    short* __restrict__ x_bf, short* __restrict__ wx, short* __restrict__ wh,
    float* __restrict__ bias_p)
{
  long i0 = (long)blockIdx.x * blockDim.x + threadIdx.x;
  long stride = (long)gridDim.x * blockDim.x;
  const long NX = (long)S_ * B_ * E_;
  const long NW = 2L * 1024 * 256;
  const long NB = 2L * 1024;

  for (long i = i0; i < NX; i += stride) x_bf[i] = (short)f2bf(x[i]);

  for (long i = i0; i < NW; i += stride) {
    int ch  = (int)(i >> 18);
    int rem = (int)(i & 262143);
    int p   = rem >> 8;
    int k   = rem & 255;
    int jc  = p >> 2, g = p & 3;
    long j  = (long)(g * 256 + jc);
    int ko  = (k & ~15) | ((k & 3) << 2) | ((k >> 2) & 3);
    wx[i] = (short)f2bf((ch ? wih_b : wih_f)[j * 256 + k]);
    wh[i] = (short)f2bf((ch ? whh_b : whh_f)[j * 256 + ko]);
  }

  for (long i = i0; i < NB; i += stride) {
    int ch = (int)(i >> 10);
    int p  = (int)(i & 1023);
    int jc = p >> 2, g = p & 3;
    int j  = g * 256 + jc;
    bias_p[i] = ch ? (bih_b[j] + bhh_b[j]) : (bih_f[j] + bhh_f[j]);
  }
}

// ---------- xz precompute (bias folded), bf16 ----------
// layout: xz[ch][t][wl 16][b 64][ll 4][ml 4][g 4], jc = wl*16 + ml*4 + ll
__global__ __launch_bounds__(512, 2) void xz_gemm3(
    const short* __restrict__ x_bf, const short* __restrict__ wx,
    const float* __restrict__ bias_p, short* __restrict__ xz)
{
  const int bid = blockIdx.x;
  const int ch = bid >> 9, t = bid & 511;
  const int tid = threadIdx.x;
  const int wave = tid >> 6, lane = tid & 63;
  const int l15 = lane & 15, l4 = lane >> 4;

  const short* W = wx + (long)ch * 1024 * 256;
  const short* X = x_bf + (long)t * B_ * E_;

  f32x4 acc[8][4];
#pragma unroll
  for (int mt = 0; mt < 8; ++mt)
#pragma unroll
    for (int nt = 0; nt < 4; ++nt) acc[mt][nt] = (f32x4){0.f, 0.f, 0.f, 0.f};

#pragma unroll
  for (int ks = 0; ks < 8; ++ks) {
    int k0 = ks * 32 + l4 * 8;
    short8 bfr[4];
#pragma unroll
    for (int nt = 0; nt < 4; ++nt)
      bfr[nt] = *(const short8*)(X + (long)(nt * 16 + l15) * E_ + k0);
#pragma unroll
    for (int mt = 0; mt < 8; ++mt) {
      int p = (wave * 8 + mt) * 16 + l15;
      short8 af = *(const short8*)(W + (long)p * 256 + k0);
#pragma unroll
      for (int nt = 0; nt < 4; ++nt)
        acc[mt][nt] = __builtin_amdgcn_mfma_f32_16x16x32_bf16(af, bfr[nt], acc[mt][nt], 0, 0, 0);
    }
  }

#pragma unroll
  for (int mt = 0; mt < 8; ++mt) {
    int jc = (wave * 8 + mt) * 4 + l4;
    int wl = jc >> 4, ml = (jc >> 2) & 3, ll = jc & 3;
    f32x4 b4 = *(const f32x4*)(bias_p + ch * 1024 + jc * 4);
#pragma unroll
    for (int nt = 0; nt < 4; ++nt) {
      int b = nt * 16 + l15;
      u16x4 v;
#pragma unroll
      for (int g = 0; g < 4; ++g) v[g] = f2bf(acc[mt][nt][g] + b4[g]);
      long off = ((((long)ch * 512 + t) * 16 + wl) * 64 + b) * 64 + ll * 16 + ml * 4;
      *(u16x4*)(xz + off) = v;
    }
  }
}

// ---------- v4 LSTM: 8 waves, 8 M-tiles/wave: 4 reg + 2 LDS + 2 L2-streamed ----------
// grid 8: ch = bid>>2, batch-slice bs = bid&3 (16 cols). 512 threads, cap 256 VGPR.
__global__ __launch_bounds__(512, 2) void lstm4(
    const short* __restrict__ wh, const short* __restrict__ xz,
    float* __restrict__ out)
{
  const int ch = blockIdx.x >> 2;
  const int bs = blockIdx.x & 3;
  const int tid = threadIdx.x;
  const int wave = tid >> 6, lane = tid & 63;
  const int l15 = lane & 15, l4 = lane >> 4;
  const int bloc = l15;
  const int bglob = bs * 16 + l15;
  const int swz = (l15 & 7) << 4;

  __shared__ short w_lds[8 * 2 * 16 * 256];  // 128 KB: per wave tiles mt=4,5 (rows +64..95)
  __shared__ short h_lds[2 * 16 * 256];      // 16 KB double buffer

  const short* whc = wh + (long)ch * 1024 * 256;

  // ---- stage LDS tiles (rows wave*128+64 .. +95), swizzled; zero h ----
  {
    char* wl = (char*)w_lds;
#pragma unroll
    for (int c = 0; c < 16; ++c) {
      int idx = c * 64 + lane;
      int row = idx >> 5;            // 0..31
      int c16 = idx & 31;
      short8 v = *(const short8*)(whc + (long)(wave * 128 + 64 + row) * 256 + c16 * 8);
      int boff = wave * 16384 + row * 512 + ((c16 * 16) ^ ((row & 7) << 4));
      *(short8*)(wl + boff) = v;
    }
    for (int i = tid; i < 2 * 16 * 256; i += 512) h_lds[i] = 0;
  }

  // ---- register tiles mt 0..3 (rows wave*128 + mt*16), pinned via opaque asm ----
  short8 ah[4][8];
#pragma unroll
  for (int mt = 0; mt < 4; ++mt)
#pragma unroll
    for (int ks = 0; ks < 8; ++ks)
      ah[mt][ks] = *(const short8*)(whc + (long)(wave * 128 + mt * 16 + l15) * 256 + ks * 32 + l4 * 8);
#pragma unroll
  for (int mt = 0; mt < 4; ++mt)
#pragma unroll
    for (int ks = 0; ks < 8; ++ks)
      asm volatile("" : "+v"(ah[mt][ks]));   // opaque def: not rematerializable/sinkable

  // ---- L2-stream bases: tiles mt=6 (rows +96) and mt=7 (rows +112) ----
  const short* w6b = whc + (long)(wave * 128 + 96 + l15) * 256 + l4 * 8;
  const short* w7b = whc + (long)(wave * 128 + 112 + l15) * 256 + l4 * 8;
  const short* xzb = xz + (((long)ch * 512 * 16 + 2 * wave) * 4096) + bglob * 64 + l4 * 16;

  float cst[8], hmax[8];
#pragma unroll
  for (int mt = 0; mt < 8; ++mt) { cst[mt] = 0.f; hmax[mt] = -2.f; }

  __syncthreads();

  const char* hlr = (const char*)h_lds;
  const char* wlc = (const char*)w_lds + wave * 16384 + l15 * 512;
  char* hlw = (char*)h_lds;
  int soff = 0;  // opaque per-iteration: defeats LICM on stream loads

  for (int t = 0; t < NSTEP; ++t) {
    int tok;
    if (ch == 0) tok = (t + 1) >> 1;
    else         tok = (t == NSTEP - 1) ? (S_ - 1) : ((t & 1) ? (t >> 1) : (t >> 1) + 1);

    asm volatile("" : "+v"(soff));
    const short* p6 = w6b + soff;
    const short* p7 = w7b + soff;

    // stream batch 1 (ks 0..3)
    short8 s6[4], s7[4];
#pragma unroll
    for (int k = 0; k < 4; ++k) {
      s6[k] = *(const short8*)(p6 + k * 32);
      s7[k] = *(const short8*)(p7 + k * 32);
    }

    // xz addends for this step (consumed at gate phase)
    const short* xp = xzb + (long)tok * 65536;
    u16x8 xq0 = *(const u16x8*)(xp);
    u16x8 xq1 = *(const u16x8*)(xp + 8);
    u16x8 xq2 = *(const u16x8*)(xp + 4096);
    u16x8 xq3 = *(const u16x8*)(xp + 4104);

    f32x4 acc[8];
#pragma unroll
    for (int mt = 0; mt < 8; ++mt) acc[mt] = (f32x4){0.f, 0.f, 0.f, 0.f};

    const int pr = ((t + 1) & 1) * 8192;

    // ---- phase A: ks 0..3 ----
#pragma unroll
    for (int ks = 0; ks < 4; ++ks) {
      int koff = ks * 64 + l4 * 16;
      short8 hfr = *(const short8*)(hlr + pr + bloc * 512 + (koff ^ swz));
      short8 w4  = *(const short8*)(wlc + (koff ^ swz));
      short8 w5  = *(const short8*)(wlc + 8192 + (koff ^ swz));
      acc[0] = __builtin_amdgcn_mfma_f32_16x16x32_bf16(ah[0][ks], hfr, acc[0], 0, 0, 0);
      acc[1] = __builtin_amdgcn_mfma_f32_16x16x32_bf16(ah[1][ks], hfr, acc[1], 0, 0, 0);
      acc[2] = __builtin_amdgcn_mfma_f32_16x16x32_bf16(ah[2][ks], hfr, acc[2], 0, 0, 0);
      acc[3] = __builtin_amdgcn_mfma_f32_16x16x32_bf16(ah[3][ks], hfr, acc[3], 0, 0, 0);
      acc[4] = __builtin_amdgcn_mfma_f32_16x16x32_bf16(w4, hfr, acc[4], 0, 0, 0);
      acc[5] = __builtin_amdgcn_mfma_f32_16x16x32_bf16(w5, hfr, acc[5], 0, 0, 0);
      acc[6] = __builtin_amdgcn_mfma_f32_16x16x32_bf16(s6[ks], hfr, acc[6], 0, 0, 0);
      acc[7] = __builtin_amdgcn_mfma_f32_16x16x32_bf16(s7[ks], hfr, acc[7], 0, 0, 0);
    }

    // stream batch 2 (ks 4..7) — batch-1 regs dead, reuse
    short8 t6[4], t7[4];
#pragma unroll
    for (int k = 0; k < 4; ++k) {
      t6[k] = *(const short8*)(p6 + 128 + k * 32);
      t7[k] = *(const short8*)(p7 + 128 + k * 32);
    }

    // ---- phase B: ks 4..7 ----
#pragma unroll
    for (int ks = 4; ks < 8; ++ks) {
      int koff = ks * 64 + l4 * 16;
      short8 hfr = *(const short8*)(hlr + pr + bloc * 512 + (koff ^ swz));
      short8 w4  = *(const short8*)(wlc + (koff ^ swz));
      short8 w5  = *(const short8*)(wlc + 8192 + (koff ^ swz));
      acc[0] = __builtin_amdgcn_mfma_f32_16x16x32_bf16(ah[0][ks], hfr, acc[0], 0, 0, 0);
      acc[1] = __builtin_amdgcn_mfma_f32_16x16x32_bf16(ah[1][ks], hfr, acc[1], 0, 0, 0);
      acc[2] = __builtin_amdgcn_mfma_f32_16x16x32_bf16(ah[2][ks], hfr, acc[2], 0, 0, 0);
      acc[3] = __builtin_amdgcn_mfma_f32_16x16x32_bf16(ah[3][ks], hfr, acc[3], 0, 0, 0);
      acc[4] = __builtin_amdgcn_mfma_f32_16x16x32_bf16(w4, hfr, acc[4], 0, 0, 0);
      acc[5] = __builtin_amdgcn_mfma_f32_16x16x32_bf16(w5, hfr, acc[5], 0, 0, 0);
      acc[6] = __builtin_amdgcn_mfma_f32_16x16x32_bf16(t6[ks - 4], hfr, acc[6], 0, 0, 0);
      acc[7] = __builtin_amdgcn_mfma_f32_16x16x32_bf16(t7[ks - 4], hfr, acc[7], 0, 0, 0);
    }

    // ---- gates / state / h write ----
    unsigned short hv[8];
#pragma unroll
    for (int mt = 0; mt < 8; ++mt) {
      const u16x8& q = (mt < 2) ? xq0 : (mt < 4) ? xq1 : (mt < 6) ? xq2 : xq3;
      const int o = (mt & 1) * 4;
      float zi = acc[mt][0] + bf2f(q[o]);
      float zf = acc[mt][1] + bf2f(q[o + 1]);
      float zg = acc[mt][2] + bf2f(q[o + 2]);
      float zo = acc[mt][3] + bf2f(q[o + 3]);
      float cc = cst[mt];
      cc = sigm(zf) * cc + sigm(zi) * tanh_(zg);
      float hh = sigm(zo) * tanh_(cc);
      cst[mt] = cc;
      hmax[mt] = fmaxf(hmax[mt], hh);
      hv[mt] = f2bf(hh);
    }
    {
      char* hw = hlw + (t & 1) * 8192 + bloc * 512;
      u16x4 a = {hv[0], hv[1], hv[2], hv[3]};
      u16x4 b = {hv[4], hv[5], hv[6], hv[7]};
      *(u16x4*)(hw + ((wave * 64 + l4 * 8) ^ swz)) = a;
      *(u16x4*)(hw + ((wave * 64 + l4 * 8 + 32) ^ swz)) = b;
    }

    __syncthreads();
  }

#pragma unroll
  for (int mt = 0; mt < 8; ++mt) {
    int jc = wave * 32 + mt * 4 + l4;
    out[(long)bglob * (2 * H_) + ch * H_ + jc] = hmax[mt];
  }
}

// ---------- fallback (no xz workspace): v3 structure, MODE 0 ----------
__global__ __launch_bounds__(1024, 4) void lstm_fb(
    const short* __restrict__ x_bf, const short* __restrict__ wx,
    const short* __restrict__ wh, const float* __restrict__ bias_p,
    float* __restrict__ out)
{
  const int ch = blockIdx.x >> 2;
  const int bs = blockIdx.x & 3;
  const int tid = threadIdx.x;
  const int wave = tid >> 6, lane = tid & 63;
  const int l15 = lane & 15, l4 = lane >> 4;
  const int bloc = l15;
  const int bglob = bs * 16 + l15;

  __shared__ short w_lds[16 * 16 * 256];
  __shared__ short h_lds[2 * 16 * 256];

  const short* whc = wh + (long)ch * 1024 * 256;
  const short* wxc = wx + (long)ch * 1024 * 256;

  {
    char* wl = (char*)w_lds;
#pragma unroll
    for (int c = 0; c < 8; ++c) {
      int chunk = c * 64 + lane;
      int row = chunk >> 5;
      int c16 = chunk & 31;
      short8 v = *(const short8*)(whc + (long)(wave * 64 + 48 + row) * 256 + c16 * 8);
      int boff = wave * 8192 + row * 512 + ((c16 * 16) ^ ((row & 7) << 4));
      *(short8*)(wl + boff) = v;
    }
    for (int i = tid; i < 2 * 16 * 256; i += 1024) h_lds[i] = 0;
  }

  short8 ah[3][8];
#pragma unroll
  for (int mt = 0; mt < 3; ++mt)
#pragma unroll
    for (int ks = 0; ks < 8; ++ks)
      ah[mt][ks] = *(const short8*)(whc + (long)(wave * 64 + mt * 16 + l15) * 256 + ks * 32 + l4 * 8);

  f32x4 bias4v[4];
#pragma unroll
  for (int mt = 0; mt < 4; ++mt)
    bias4v[mt] = *(const f32x4*)(bias_p + ch * 1024 + (wave * 16 + mt * 4 + l4) * 4);

  float cst[4], hmax[4];
#pragma unroll
  for (int mt = 0; mt < 4; ++mt) { cst[mt] = 0.f; hmax[mt] = -2.f; }

  __syncthreads();

  const char* hlr = (const char*)h_lds;
  const char* wlr = (const char*)w_lds;
  char* hlw = (char*)h_lds;
  const int swzb = (bloc & 7) << 4;
  const int wboff = wave * 8192 + l15 * 512;
  const int q0b = (wave * 16 + l4 * 4) * 2;

  for (int t = 0; t < NSTEP; ++t) {
    int tok;
    if (ch == 0) tok = (t + 1) >> 1;
    else         tok = (t == NSTEP - 1) ? (S_ - 1) : ((t & 1) ? (t >> 1) : (t >> 1) + 1);

    f32x4 acc[4];
#pragma unroll
    for (int mt = 0; mt < 4; ++mt) acc[mt] = (f32x4){0.f, 0.f, 0.f, 0.f};

    const short* xr = x_bf + ((long)tok * B_ + bglob) * E_;
#pragma unroll
    for (int ks = 0; ks < 8; ++ks) {
      int k0 = ks * 32 + l4 * 8;
      short8 bx = *(const short8*)(xr + k0);
#pragma unroll
      for (int mt = 0; mt < 4; ++mt) {
        short8 axf = *(const short8*)(wxc + (long)(wave * 64 + mt * 16 + l15) * 256 + k0);
        acc[mt] = __builtin_amdgcn_mfma_f32_16x16x32_bf16(axf, bx, acc[mt], 0, 0, 0);
      }
    }

    const int hbase = (((t + 1) & 1) * 8192) + bloc * 512;
#pragma unroll
    for (int ks = 0; ks < 8; ++ks) {
      int koff = ks * 64 + l4 * 16;
      short8 hfr = *(const short8*)(hlr + hbase + (koff ^ swzb));
      acc[0] = __builtin_amdgcn_mfma_f32_16x16x32_bf16(ah[0][ks], hfr, acc[0], 0, 0, 0);
      acc[1] = __builtin_amdgcn_mfma_f32_16x16x32_bf16(ah[1][ks], hfr, acc[1], 0, 0, 0);
      acc[2] = __builtin_amdgcn_mfma_f32_16x16x32_bf16(ah[2][ks], hfr, acc[2], 0, 0, 0);
      short8 wfr = *(const short8*)(wlr + wboff + (koff ^ ((l15 & 7) << 4)));
      acc[3] = __builtin_amdgcn_mfma_f32_16x16x32_bf16(wfr, hfr, acc[3], 0, 0, 0);
    }

    unsigned short hv[4];
#pragma unroll
    for (int mt = 0; mt < 4; ++mt) {
      float zi = acc[mt][0] + bias4v[mt][0];
      float zf = acc[mt][1] + bias4v[mt][1];
      float zg = acc[mt][2] + bias4v[mt][2];
      float zo = acc[mt][3] + bias4v[mt][3];
      float cc = cst[mt];
      cc = sigm(zf) * cc + sigm(zi) * tanh_(zg);
      float hh = sigm(zo) * tanh_(cc);
      cst[mt] = cc;
      hmax[mt] = fmaxf(hmax[mt], hh);
      hv[mt] = f2bf(hh);
    }
    {
      u16x4 hw4 = {hv[0], hv[1], hv[2], hv[3]};
      int wb = ((t & 1) * 8192) + bloc * 512 + (q0b ^ swzb);
      *(u16x4*)(hlw + wb) = hw4;
    }

    __syncthreads();
  }

#pragma unroll
  for (int mt = 0; mt < 4; ++mt) {
    int jc = wave * 16 + mt * 4 + l4;
    out[(long)bglob * (2 * H_) + ch * H_ + jc] = hmax[mt];
  }
}

extern "C" void kernel_launch(void* const* d_in, const int* in_sizes, int n_in,
                              void* d_out, int out_size, void* d_ws, size_t ws_size,
                              hipStream_t stream) {
  const float* x     = (const float*)d_in[0];
  const float* wih_f = (const float*)d_in[1];
  const float* whh_f = (const float*)d_in[2];
  const float* bih_f = (const float*)d_in[3];
  const float* bhh_f = (const float*)d_in[4];
  const float* wih_b = (const float*)d_in[5];
  const float* whh_b = (const float*)d_in[6];
  const float* bih_b = (const float*)d_in[7];
  const float* bhh_b = (const float*)d_in[8];

  char* ws = (char*)d_ws;
  short* x_bf   = (short*)(ws);                 // 16,777,216 B
  short* wx     = (short*)(ws + 16777216);      //  1,048,576 B
  short* wh     = (short*)(ws + 17825792);      //  1,048,576 B
  float* bias_p = (float*)(ws + 18874368);      //      8,192 B
  short* xz     = (short*)(ws + 18882560);      // 134,217,728 B (bf16)

  const size_t NEED_XZ = 18882560UL + 134217728UL;   // 153,100,288
  if (ws_size < 18882560UL) return;

  prep3<<<2048, 256, 0, stream>>>(x, wih_f, whh_f, bih_f, bhh_f,
                                  wih_b, whh_b, bih_b, bhh_b,
                                  x_bf, wx, wh, bias_p);

  float* outp = (float*)d_out;
  if (ws_size >= NEED_XZ) {
    xz_gemm3<<<1024, 512, 0, stream>>>(x_bf, wx, bias_p, xz);
    lstm4<<<8, 512, 0, stream>>>(wh, xz, outp);
  } else {
    lstm_fb<<<8, 1024, 0, stream>>>(x_bf, wx, wh, bias_p, outp);
  }
}

// Round 5
// 6732.053 us; speedup vs baseline: 2.6892x; 1.0001x over previous
//
#include <hip/hip_runtime.h>

typedef __attribute__((ext_vector_type(8))) short short8;
typedef __attribute__((ext_vector_type(4))) float f32x4;
typedef __attribute__((ext_vector_type(4))) unsigned short u16x4;
typedef __attribute__((ext_vector_type(8))) unsigned short u16x8;

#define S_ 512
#define B_ 64
#define E_ 256
#define H_ 256
#define NSTEP 1023  // 2*S - 1 sequential cell steps per chain

// ---------- helpers ----------
__device__ __forceinline__ unsigned short f2bf(float f) {
  unsigned u = __builtin_bit_cast(unsigned, f);
  return (unsigned short)((u + 0x7fffu + ((u >> 16) & 1u)) >> 16);  // RNE
}
__device__ __forceinline__ float bf2f(unsigned short h) {
  unsigned u = ((unsigned)h) << 16;
  return __builtin_bit_cast(float, u);
}
__device__ __forceinline__ float sigm(float x) { return 1.f / (1.f + __expf(-x)); }
__device__ __forceinline__ float tanh_(float x) {
  x = fminf(fmaxf(x, -15.f), 15.f);
  float e = __expf(-2.f * x);
  return (1.f - e) / (1.f + e);
}

// ---------- prep ----------
// x -> bf16; wx packed rows p=jc*4+gate, natural cols; wh packed rows, PERMUTED cols:
// stored col k holds orig col (k&~15)|((k&3)<<2)|((k>>2)&3); bias combined.
__global__ __launch_bounds__(256) void prep3(
    const float* __restrict__ x,
    const float* __restrict__ wih_f, const float* __restrict__ whh_f,
    const float* __restrict__ bih_f, const float* __restrict__ bhh_f,
    const float* __restrict__ wih_b, const float* __restrict__ whh_b,
    const float* __restrict__ bih_b, const float* __restrict__ bhh_b,
    short* __restrict__ x_bf, short* __restrict__ wx, short* __restrict__ wh,
    float* __restrict__ bias_p)
{
  long i0 = (long)blockIdx.x * blockDim.x + threadIdx.x;
  long stride = (long)gridDim.x * blockDim.x;
  const long NX = (long)S_ * B_ * E_;
  const long NW = 2L * 1024 * 256;
  const long NB = 2L * 1024;

  for (long i = i0; i < NX; i += stride) x_bf[i] = (short)f2bf(x[i]);

  for (long i = i0; i < NW; i += stride) {
    int ch  = (int)(i >> 18);
    int rem = (int)(i & 262143);
    int p   = rem >> 8;
    int k   = rem & 255;
    int jc  = p >> 2, g = p & 3;
    long j  = (long)(g * 256 + jc);
    int ko  = (k & ~15) | ((k & 3) << 2) | ((k >> 2) & 3);
    wx[i] = (short)f2bf((ch ? wih_b : wih_f)[j * 256 + k]);
    wh[i] = (short)f2bf((ch ? whh_b : whh_f)[j * 256 + ko]);
  }

  for (long i = i0; i < NB; i += stride) {
    int ch = (int)(i >> 10);
    int p  = (int)(i & 1023);
    int jc = p >> 2, g = p & 3;
    int j  = g * 256 + jc;
    bias_p[i] = ch ? (bih_b[j] + bhh_b[j]) : (bih_f[j] + bhh_f[j]);
  }
}

// ---------- xz precompute (bias folded), bf16 ----------
// layout: xz[ch][t][wl 16][b 64][ll 4][ml 4][g 4], jc = wl*16 + ml*4 + ll
__global__ __launch_bounds__(512, 2) void xz_gemm3(
    const short* __restrict__ x_bf, const short* __restrict__ wx,
    const float* __restrict__ bias_p, short* __restrict__ xz)
{
  const int bid = blockIdx.x;
  const int ch = bid >> 9, t = bid & 511;
  const int tid = threadIdx.x;
  const int wave = tid >> 6, lane = tid & 63;
  const int l15 = lane & 15, l4 = lane >> 4;

  const short* W = wx + (long)ch * 1024 * 256;
  const short* X = x_bf + (long)t * B_ * E_;

  f32x4 acc[8][4];
#pragma unroll
  for (int mt = 0; mt < 8; ++mt)
#pragma unroll
    for (int nt = 0; nt < 4; ++nt) acc[mt][nt] = (f32x4){0.f, 0.f, 0.f, 0.f};

#pragma unroll
  for (int ks = 0; ks < 8; ++ks) {
    int k0 = ks * 32 + l4 * 8;
    short8 bfr[4];
#pragma unroll
    for (int nt = 0; nt < 4; ++nt)
      bfr[nt] = *(const short8*)(X + (long)(nt * 16 + l15) * E_ + k0);
#pragma unroll
    for (int mt = 0; mt < 8; ++mt) {
      int p = (wave * 8 + mt) * 16 + l15;
      short8 af = *(const short8*)(W + (long)p * 256 + k0);
#pragma unroll
      for (int nt = 0; nt < 4; ++nt)
        acc[mt][nt] = __builtin_amdgcn_mfma_f32_16x16x32_bf16(af, bfr[nt], acc[mt][nt], 0, 0, 0);
    }
  }

#pragma unroll
  for (int mt = 0; mt < 8; ++mt) {
    int jc = (wave * 8 + mt) * 4 + l4;
    int wl = jc >> 4, ml = (jc >> 2) & 3, ll = jc & 3;
    f32x4 b4 = *(const f32x4*)(bias_p + ch * 1024 + jc * 4);
#pragma unroll
    for (int nt = 0; nt < 4; ++nt) {
      int b = nt * 16 + l15;
      u16x4 v;
#pragma unroll
      for (int g = 0; g < 4; ++g) v[g] = f2bf(acc[mt][nt][g] + b4[g]);
      long off = ((((long)ch * 512 + t) * 16 + wl) * 64 + b) * 64 + ll * 16 + ml * 4;
      *(u16x4*)(xz + off) = v;
    }
  }
}

// ---------- v5 LSTM: 8 waves, 8 M-tiles/wave: 4 reg + 2 LDS + 2 L2-streamed ----------
// grid 8: ch = bid>>2, batch-slice bs = bid&3 (16 cols). 512 threads.
// amdgpu_waves_per_eu(2,2): forces allocator target to 2 waves/EU -> 256-VGPR budget.
// (Empirical: __launch_bounds__ min-arg alone does NOT lower the occupancy target;
//  v3/v4 capped at 64/128 and spilled the pinned weight tiles.)
__global__ __attribute__((amdgpu_flat_work_group_size(512, 512)))
__attribute__((amdgpu_waves_per_eu(2, 2))) void lstm5(
    const short* __restrict__ wh, const short* __restrict__ xz,
    float* __restrict__ out)
{
  const int ch = blockIdx.x >> 2;
  const int bs = blockIdx.x & 3;
  const int tid = threadIdx.x;
  const int wave = tid >> 6, lane = tid & 63;
  const int l15 = lane & 15, l4 = lane >> 4;
  const int bloc = l15;
  const int bglob = bs * 16 + l15;
  const int swz = (l15 & 7) << 4;

  __shared__ short w_lds[8 * 2 * 16 * 256];  // 128 KB: per wave tiles mt=4,5 (rows +64..95)
  __shared__ short h_lds[2 * 16 * 256];      // 16 KB double buffer

  const short* whc = wh + (long)ch * 1024 * 256;

  // ---- stage LDS tiles (rows wave*128+64 .. +95), swizzled; zero h ----
  {
    char* wl = (char*)w_lds;
#pragma unroll
    for (int c = 0; c < 16; ++c) {
      int idx = c * 64 + lane;
      int row = idx >> 5;            // 0..31
      int c16 = idx & 31;
      short8 v = *(const short8*)(whc + (long)(wave * 128 + 64 + row) * 256 + c16 * 8);
      int boff = wave * 16384 + row * 512 + ((c16 * 16) ^ ((row & 7) << 4));
      *(short8*)(wl + boff) = v;
    }
    for (int i = tid; i < 2 * 16 * 256; i += 512) h_lds[i] = 0;
  }

  // ---- register tiles mt 0..3 (rows wave*128 + mt*16), pinned via opaque asm ----
  short8 ah[4][8];
#pragma unroll
  for (int mt = 0; mt < 4; ++mt)
#pragma unroll
    for (int ks = 0; ks < 8; ++ks)
      ah[mt][ks] = *(const short8*)(whc + (long)(wave * 128 + mt * 16 + l15) * 256 + ks * 32 + l4 * 8);
#pragma unroll
  for (int mt = 0; mt < 4; ++mt)
#pragma unroll
    for (int ks = 0; ks < 8; ++ks)
      asm volatile("" : "+v"(ah[mt][ks]));   // opaque def: not rematerializable/sinkable

  // ---- L2-stream bases: tiles mt=6 (rows +96) and mt=7 (rows +112) ----
  const short* w6b = whc + (long)(wave * 128 + 96 + l15) * 256 + l4 * 8;
  const short* w7b = whc + (long)(wave * 128 + 112 + l15) * 256 + l4 * 8;
  const short* xzb = xz + (((long)ch * 512 * 16 + 2 * wave) * 4096) + bglob * 64 + l4 * 16;

  float cst[8], hmax[8];
#pragma unroll
  for (int mt = 0; mt < 8; ++mt) { cst[mt] = 0.f; hmax[mt] = -2.f; }

  __syncthreads();

  const char* hlr = (const char*)h_lds;
  const char* wlc = (const char*)w_lds + wave * 16384 + l15 * 512;
  char* hlw = (char*)h_lds;
  int soff = 0;  // opaque per-iteration: defeats LICM on stream loads

  for (int t = 0; t < NSTEP; ++t) {
    int tok;
    if (ch == 0) tok = (t + 1) >> 1;
    else         tok = (t == NSTEP - 1) ? (S_ - 1) : ((t & 1) ? (t >> 1) : (t >> 1) + 1);

    asm volatile("" : "+v"(soff));
    const short* p6 = w6b + soff;
    const short* p7 = w7b + soff;

    // xz addends first (L3 latency is longest; consumed at gate phase)
    const short* xp = xzb + (long)tok * 65536;
    u16x8 xq0 = *(const u16x8*)(xp);
    u16x8 xq1 = *(const u16x8*)(xp + 8);
    u16x8 xq2 = *(const u16x8*)(xp + 4096);
    u16x8 xq3 = *(const u16x8*)(xp + 4104);

    // stream batch 1 (ks 0..3)
    short8 s6[4], s7[4];
#pragma unroll
    for (int k = 0; k < 4; ++k) {
      s6[k] = *(const short8*)(p6 + k * 32);
      s7[k] = *(const short8*)(p7 + k * 32);
    }

    f32x4 acc[8];
#pragma unroll
    for (int mt = 0; mt < 8; ++mt) acc[mt] = (f32x4){0.f, 0.f, 0.f, 0.f};

    const int pr = ((t + 1) & 1) * 8192;

    // ---- phase A: ks 0..3 ----
#pragma unroll
    for (int ks = 0; ks < 4; ++ks) {
      int koff = ks * 64 + l4 * 16;
      short8 hfr = *(const short8*)(hlr + pr + bloc * 512 + (koff ^ swz));
      short8 w4  = *(const short8*)(wlc + (koff ^ swz));
      short8 w5  = *(const short8*)(wlc + 8192 + (koff ^ swz));
      acc[0] = __builtin_amdgcn_mfma_f32_16x16x32_bf16(ah[0][ks], hfr, acc[0], 0, 0, 0);
      acc[1] = __builtin_amdgcn_mfma_f32_16x16x32_bf16(ah[1][ks], hfr, acc[1], 0, 0, 0);
      acc[2] = __builtin_amdgcn_mfma_f32_16x16x32_bf16(ah[2][ks], hfr, acc[2], 0, 0, 0);
      acc[3] = __builtin_amdgcn_mfma_f32_16x16x32_bf16(ah[3][ks], hfr, acc[3], 0, 0, 0);
      acc[4] = __builtin_amdgcn_mfma_f32_16x16x32_bf16(w4, hfr, acc[4], 0, 0, 0);
      acc[5] = __builtin_amdgcn_mfma_f32_16x16x32_bf16(w5, hfr, acc[5], 0, 0, 0);
      acc[6] = __builtin_amdgcn_mfma_f32_16x16x32_bf16(s6[ks], hfr, acc[6], 0, 0, 0);
      acc[7] = __builtin_amdgcn_mfma_f32_16x16x32_bf16(s7[ks], hfr, acc[7], 0, 0, 0);
    }

    // stream batch 2 (ks 4..7) — batch-1 regs dead, reuse
    short8 t6[4], t7[4];
#pragma unroll
    for (int k = 0; k < 4; ++k) {
      t6[k] = *(const short8*)(p6 + 128 + k * 32);
      t7[k] = *(const short8*)(p7 + 128 + k * 32);
    }

    // ---- phase B: ks 4..7 ----
#pragma unroll
    for (int ks = 4; ks < 8; ++ks) {
      int koff = ks * 64 + l4 * 16;
      short8 hfr = *(const short8*)(hlr + pr + bloc * 512 + (koff ^ swz));
      short8 w4  = *(const short8*)(wlc + (koff ^ swz));
      short8 w5  = *(const short8*)(wlc + 8192 + (koff ^ swz));
      acc[0] = __builtin_amdgcn_mfma_f32_16x16x32_bf16(ah[0][ks], hfr, acc[0], 0, 0, 0);
      acc[1] = __builtin_amdgcn_mfma_f32_16x16x32_bf16(ah[1][ks], hfr, acc[1], 0, 0, 0);
      acc[2] = __builtin_amdgcn_mfma_f32_16x16x32_bf16(ah[2][ks], hfr, acc[2], 0, 0, 0);
      acc[3] = __builtin_amdgcn_mfma_f32_16x16x32_bf16(ah[3][ks], hfr, acc[3], 0, 0, 0);
      acc[4] = __builtin_amdgcn_mfma_f32_16x16x32_bf16(w4, hfr, acc[4], 0, 0, 0);
      acc[5] = __builtin_amdgcn_mfma_f32_16x16x32_bf16(w5, hfr, acc[5], 0, 0, 0);
      acc[6] = __builtin_amdgcn_mfma_f32_16x16x32_bf16(t6[ks - 4], hfr, acc[6], 0, 0, 0);
      acc[7] = __builtin_amdgcn_mfma_f32_16x16x32_bf16(t7[ks - 4], hfr, acc[7], 0, 0, 0);
    }

    // ---- gates / state / h write ----
    unsigned short hv[8];
#pragma unroll
    for (int mt = 0; mt < 8; ++mt) {
      const u16x8& q = (mt < 2) ? xq0 : (mt < 4) ? xq1 : (mt < 6) ? xq2 : xq3;
      const int o = (mt & 1) * 4;
      float zi = acc[mt][0] + bf2f(q[o]);
      float zf = acc[mt][1] + bf2f(q[o + 1]);
      float zg = acc[mt][2] + bf2f(q[o + 2]);
      float zo = acc[mt][3] + bf2f(q[o + 3]);
      float cc = cst[mt];
      cc = sigm(zf) * cc + sigm(zi) * tanh_(zg);
      float hh = sigm(zo) * tanh_(cc);
      cst[mt] = cc;
      hmax[mt] = fmaxf(hmax[mt], hh);
      hv[mt] = f2bf(hh);
    }
    {
      char* hw = hlw + (t & 1) * 8192 + bloc * 512;
      u16x4 a = {hv[0], hv[1], hv[2], hv[3]};
      u16x4 b = {hv[4], hv[5], hv[6], hv[7]};
      *(u16x4*)(hw + ((wave * 64 + l4 * 8) ^ swz)) = a;
      *(u16x4*)(hw + ((wave * 64 + l4 * 8 + 32) ^ swz)) = b;
    }

    __syncthreads();
  }

#pragma unroll
  for (int mt = 0; mt < 8; ++mt) {
    int jc = wave * 32 + mt * 4 + l4;
    out[(long)bglob * (2 * H_) + ch * H_ + jc] = hmax[mt];
  }
}

// ---------- fallback (no xz workspace): v3 structure, MODE 0 ----------
__global__ __launch_bounds__(1024, 4) void lstm_fb(
    const short* __restrict__ x_bf, const short* __restrict__ wx,
    const short* __restrict__ wh, const float* __restrict__ bias_p,
    float* __restrict__ out)
{
  const int ch = blockIdx.x >> 2;
  const int bs = blockIdx.x & 3;
  const int tid = threadIdx.x;
  const int wave = tid >> 6, lane = tid & 63;
  const int l15 = lane & 15, l4 = lane >> 4;
  const int bloc = l15;
  const int bglob = bs * 16 + l15;

  __shared__ short w_lds[16 * 16 * 256];
  __shared__ short h_lds[2 * 16 * 256];

  const short* whc = wh + (long)ch * 1024 * 256;
  const short* wxc = wx + (long)ch * 1024 * 256;

  {
    char* wl = (char*)w_lds;
#pragma unroll
    for (int c = 0; c < 8; ++c) {
      int chunk = c * 64 + lane;
      int row = chunk >> 5;
      int c16 = chunk & 31;
      short8 v = *(const short8*)(whc + (long)(wave * 64 + 48 + row) * 256 + c16 * 8);
      int boff = wave * 8192 + row * 512 + ((c16 * 16) ^ ((row & 7) << 4));
      *(short8*)(wl + boff) = v;
    }
    for (int i = tid; i < 2 * 16 * 256; i += 1024) h_lds[i] = 0;
  }

  short8 ah[3][8];
#pragma unroll
  for (int mt = 0; mt < 3; ++mt)
#pragma unroll
    for (int ks = 0; ks < 8; ++ks)
      ah[mt][ks] = *(const short8*)(whc + (long)(wave * 64 + mt * 16 + l15) * 256 + ks * 32 + l4 * 8);

  f32x4 bias4v[4];
#pragma unroll
  for (int mt = 0; mt < 4; ++mt)
    bias4v[mt] = *(const f32x4*)(bias_p + ch * 1024 + (wave * 16 + mt * 4 + l4) * 4);

  float cst[4], hmax[4];
#pragma unroll
  for (int mt = 0; mt < 4; ++mt) { cst[mt] = 0.f; hmax[mt] = -2.f; }

  __syncthreads();

  const char* hlr = (const char*)h_lds;
  const char* wlr = (const char*)w_lds;
  char* hlw = (char*)h_lds;
  const int swzb = (bloc & 7) << 4;
  const int wboff = wave * 8192 + l15 * 512;
  const int q0b = (wave * 16 + l4 * 4) * 2;

  for (int t = 0; t < NSTEP; ++t) {
    int tok;
    if (ch == 0) tok = (t + 1) >> 1;
    else         tok = (t == NSTEP - 1) ? (S_ - 1) : ((t & 1) ? (t >> 1) : (t >> 1) + 1);

    f32x4 acc[4];
#pragma unroll
    for (int mt = 0; mt < 4; ++mt) acc[mt] = (f32x4){0.f, 0.f, 0.f, 0.f};

    const short* xr = x_bf + ((long)tok * B_ + bglob) * E_;
#pragma unroll
    for (int ks = 0; ks < 8; ++ks) {
      int k0 = ks * 32 + l4 * 8;
      short8 bx = *(const short8*)(xr + k0);
#pragma unroll
      for (int mt = 0; mt < 4; ++mt) {
        short8 axf = *(const short8*)(wxc + (long)(wave * 64 + mt * 16 + l15) * 256 + k0);
        acc[mt] = __builtin_amdgcn_mfma_f32_16x16x32_bf16(axf, bx, acc[mt], 0, 0, 0);
      }
    }

    const int hbase = (((t + 1) & 1) * 8192) + bloc * 512;
#pragma unroll
    for (int ks = 0; ks < 8; ++ks) {
      int koff = ks * 64 + l4 * 16;
      short8 hfr = *(const short8*)(hlr + hbase + (koff ^ swzb));
      acc[0] = __builtin_amdgcn_mfma_f32_16x16x32_bf16(ah[0][ks], hfr, acc[0], 0, 0, 0);
      acc[1] = __builtin_amdgcn_mfma_f32_16x16x32_bf16(ah[1][ks], hfr, acc[1], 0, 0, 0);
      acc[2] = __builtin_amdgcn_mfma_f32_16x16x32_bf16(ah[2][ks], hfr, acc[2], 0, 0, 0);
      short8 wfr = *(const short8*)(wlr + wboff + (koff ^ ((l15 & 7) << 4)));
      acc[3] = __builtin_amdgcn_mfma_f32_16x16x32_bf16(wfr, hfr, acc[3], 0, 0, 0);
    }

    unsigned short hv[4];
#pragma unroll
    for (int mt = 0; mt < 4; ++mt) {
      float zi = acc[mt][0] + bias4v[mt][0];
      float zf = acc[mt][1] + bias4v[mt][1];
      float zg = acc[mt][2] + bias4v[mt][2];
      float zo = acc[mt][3] + bias4v[mt][3];
      float cc = cst[mt];
      cc = sigm(zf) * cc + sigm(zi) * tanh_(zg);
      float hh = sigm(zo) * tanh_(cc);
      cst[mt] = cc;
      hmax[mt] = fmaxf(hmax[mt], hh);
      hv[mt] = f2bf(hh);
    }
    {
      u16x4 hw4 = {hv[0], hv[1], hv[2], hv[3]};
      int wb = ((t & 1) * 8192) + bloc * 512 + (q0b ^ swzb);
      *(u16x4*)(hlw + wb) = hw4;
    }

    __syncthreads();
  }

#pragma unroll
  for (int mt = 0; mt < 4; ++mt) {
    int jc = wave * 16 + mt * 4 + l4;
    out[(long)bglob * (2 * H_) + ch * H_ + jc] = hmax[mt];
  }
}

extern "C" void kernel_launch(void* const* d_in, const int* in_sizes, int n_in,
                              void* d_out, int out_size, void* d_ws, size_t ws_size,
                              hipStream_t stream) {
  const float* x     = (const float*)d_in[0];
  const float* wih_f = (const float*)d_in[1];
  const float* whh_f = (const float*)d_in[2];
  const float* bih_f = (const float*)d_in[3];
  const float* bhh_f = (const float*)d_in[4];
  const float* wih_b = (const float*)d_in[5];
  const float* whh_b = (const float*)d_in[6];
  const float* bih_b = (const float*)d_in[7];
  const float* bhh_b = (const float*)d_in[8];

  char* ws = (char*)d_ws;
  short* x_bf   = (short*)(ws);                 // 16,777,216 B
  short* wx     = (short*)(ws + 16777216);      //  1,048,576 B
  short* wh     = (short*)(ws + 17825792);      //  1,048,576 B
  float* bias_p = (float*)(ws + 18874368);      //      8,192 B
  short* xz     = (short*)(ws + 18882560);      // 134,217,728 B (bf16)

  const size_t NEED_XZ = 18882560UL + 134217728UL;   // 153,100,288
  if (ws_size < 18882560UL) return;

  prep3<<<2048, 256, 0, stream>>>(x, wih_f, whh_f, bih_f, bhh_f,
                                  wih_b, whh_b, bih_b, bhh_b,
                                  x_bf, wx, wh, bias_p);

  float* outp = (float*)d_out;
  if (ws_size >= NEED_XZ) {
    xz_gemm3<<<1024, 512, 0, stream>>>(x_bf, wx, bias_p, xz);
    lstm5<<<8, 512, 0, stream>>>(wh, xz, outp);
  } else {
    lstm_fb<<<8, 1024, 0, stream>>>(x_bf, wx, wh, bias_p, outp);
  }
}